// Round 4
// baseline (191.169 us; speedup 1.0000x reference)
//
#include <hip/hip_runtime.h>

// out[b][j] = x[b][(j - s_b) mod T]
//
// Barrier-free funnel-shift version. Each wave owns a contiguous span of one
// row. Per iteration: lane L loads the 16B-ALIGNED quad at src = qb+i*252+4L
// (wrapped mod T, stays aligned since T%4==0). The wave-uniform misalignment
// off = (c0 - s) mod 4 is fixed in-register: result quad = elements off..off+3
// of [q_L, q_{L+1}], with q_{L+1} fetched via __shfl_down(.,1). Lanes 0..62
// store aligned float4s; the wave advances 252 floats/iter (lane 63's quad is
// the overlap). No LDS buffer, no __syncthreads, 4-deep load pipeline.

#define WPR 32  // waves per row (256 rows * 32 = 8192 waves = 32/CU)

__global__ __launch_bounds__(256) void roll_rows_funnel(
    const float* __restrict__ x,
    const int* __restrict__ shifts,
    float* __restrict__ out,
    int T, int span) {
    const int tid = blockIdx.x * 256 + threadIdx.x;
    const int w = tid >> 6;          // global wave id (wave-uniform)
    const int L = threadIdx.x & 63;  // lane
    const int r = w / WPR;           // row
    const int k = w - r * WPR;       // span slot within row

    const int c0 = k * span;         // first output column (wave-uniform)
    if (c0 >= T) return;             // uniform exit
    const int len = min(span, T - c0);  // multiple of 4

    int s = shifts[r] % T;
    if (s < 0) s += T;

    const int base = c0 - s;         // first source float needed
    const int off = base & 3;        // wave-uniform misalignment, in [0,3]
    const int qb = base - off;       // aligned source start, >= -(T+2)

    const float* __restrict__ xr = x + (size_t)r * (size_t)T;
    float* __restrict__ orow = out + (size_t)r * (size_t)T + c0;

    const int iters = (len + 251) / 252;

    if (off == 0) {
        for (int i0 = 0; i0 < iters; i0 += 4) {
            float4 q[4];
#pragma unroll
            for (int u = 0; u < 4; ++u) {           // issue 4 independent loads
                const int ii = min(i0 + u, iters - 1);
                int src = qb + ii * 252 + 4 * L;
                if (src < 0) src += T;
                else if (src >= T) src -= T;        // aligned, in [0, T-4]
                q[u] = *reinterpret_cast<const float4*>(xr + src);
            }
#pragma unroll
            for (int u = 0; u < 4; ++u) {
                const int jo = (i0 + u) * 252 + 4 * L;
                if (L < 63 && jo < len)
                    *reinterpret_cast<float4*>(orow + jo) = q[u];
            }
        }
    } else {
        for (int i0 = 0; i0 < iters; i0 += 4) {
            float4 q[4];
#pragma unroll
            for (int u = 0; u < 4; ++u) {
                const int ii = min(i0 + u, iters - 1);
                int src = qb + ii * 252 + 4 * L;
                if (src < 0) src += T;
                else if (src >= T) src -= T;
                q[u] = *reinterpret_cast<const float4*>(xr + src);
            }
#pragma unroll
            for (int u = 0; u < 4; ++u) {
                // neighbor quad's leading floats (all lanes active here)
                const float a0 = __shfl_down(q[u].x, 1, 64);
                const float a1 = __shfl_down(q[u].y, 1, 64);
                const float a2 = __shfl_down(q[u].z, 1, 64);
                float4 rr;
                if (off == 1)      rr = make_float4(q[u].y, q[u].z, q[u].w, a0);
                else if (off == 2) rr = make_float4(q[u].z, q[u].w, a0, a1);
                else               rr = make_float4(q[u].w, a0, a1, a2);
                const int jo = (i0 + u) * 252 + 4 * L;
                if (L < 63 && jo < len)
                    *reinterpret_cast<float4*>(orow + jo) = rr;
            }
        }
    }
}

// Generic scalar fallback (T not divisible by 4).
__global__ void roll_rows_scalar(const float* __restrict__ x,
                                 const int* __restrict__ shifts,
                                 float* __restrict__ out,
                                 int T) {
    const int b = blockIdx.y;
    const int j = blockIdx.x * blockDim.x + threadIdx.x;
    if (j >= T) return;
    int s = shifts[b] % T;
    if (s < 0) s += T;
    int i = j - s;
    if (i < 0) i += T;
    out[(size_t)b * T + j] = x[(size_t)b * T + i];
}

extern "C" void kernel_launch(void* const* d_in, const int* in_sizes, int n_in,
                              void* d_out, int out_size, void* d_ws, size_t ws_size,
                              hipStream_t stream) {
    const float* x = (const float*)d_in[0];
    const int* shifts = (const int*)d_in[1];
    float* out = (float*)d_out;

    const int B = in_sizes[1];
    const int T = in_sizes[0] / B;

    if ((T & 3) == 0) {
        // span per wave, rounded up to a multiple of 4
        const int span = (((T + WPR - 1) / WPR) + 3) & ~3;
        const int total_waves = B * WPR;
        const int blocks = total_waves / 4;  // 4 waves (256 threads) per block
        roll_rows_funnel<<<blocks, 256, 0, stream>>>(x, shifts, out, T, span);
    } else {
        dim3 block(256);
        dim3 grid((T + 255) / 256, B);
        roll_rows_scalar<<<grid, block, 0, stream>>>(x, shifts, out, T);
    }
}

// Round 5
// 182.243 us; speedup vs baseline: 1.0490x; 1.0490x over previous
//
#include <hip/hip_runtime.h>

// out[b][j] = x[b][(j - s_b) mod T]
//
// Minimal-instruction copy shape: per 16B of output exactly ONE global load
// and ONE global store. The shift misalignment is absorbed by the LOAD side
// using hardware-unaligned global_load_dwordx4 (align-4 vector typedef).
// Stores are 16B-aligned and non-temporal (output is never re-read; keep the
// LLC for the x read stream, which the harness restore leaves resident).
// No LDS, no barrier, no shuffles. 4 independent quads per thread for MLP.

typedef float v4f __attribute__((ext_vector_type(4)));
typedef v4f v4f_u __attribute__((aligned(4)));   // reduced-alignment view

#define QPT 4  // quads (float4s) per thread

__global__ __launch_bounds__(256) void roll_rows_ux4(
    const float* __restrict__ x,
    const int* __restrict__ shifts,
    float* __restrict__ out,
    int T) {
    const int r = blockIdx.y;
    const int q0 = blockIdx.x * (256 * QPT) + threadIdx.x;  // quad idx, stride 256 per u
    const int TQ = T >> 2;

    int s = shifts[r] % T;
    if (s < 0) s += T;

    const float* __restrict__ xr = x + (size_t)r * (size_t)T;
    float* __restrict__ orow = out + (size_t)r * (size_t)T;

    v4f v[QPT];
    int src[QPT];
    bool fast[QPT];

    // ---- issue all loads first (independent -> stay in flight) ----
#pragma unroll
    for (int u = 0; u < QPT; ++u) {
        const int q = q0 + u * 256;
        int sc = q * 4 - s;
        if (sc < 0) sc += T;            // sc in [0, T)
        src[u] = sc;
        fast[u] = (q < TQ) && (sc <= T - 4);
        if (fast[u])
            v[u] = *reinterpret_cast<const v4f_u*>(xr + sc);  // HW-unaligned 16B load
    }

    // ---- patch rare wrap-crossing quads, then store aligned+nontemporal ----
#pragma unroll
    for (int u = 0; u < QPT; ++u) {
        const int q = q0 + u * 256;
        if (q < TQ) {
            if (!fast[u]) {             // <=1 quad per row crosses the wrap
                float tmp[4];
#pragma unroll
                for (int e = 0; e < 4; ++e) {
                    int si = src[u] + e;
                    if (si >= T) si -= T;
                    tmp[e] = xr[si];
                }
                v[u] = (v4f){tmp[0], tmp[1], tmp[2], tmp[3]};
            }
            __builtin_nontemporal_store(v[u], reinterpret_cast<v4f*>(orow + q * 4));
        }
    }
}

// Generic scalar fallback (T not divisible by 4).
__global__ void roll_rows_scalar(const float* __restrict__ x,
                                 const int* __restrict__ shifts,
                                 float* __restrict__ out,
                                 int T) {
    const int b = blockIdx.y;
    const int j = blockIdx.x * blockDim.x + threadIdx.x;
    if (j >= T) return;
    int s = shifts[b] % T;
    if (s < 0) s += T;
    int i = j - s;
    if (i < 0) i += T;
    out[(size_t)b * T + j] = x[(size_t)b * T + i];
}

extern "C" void kernel_launch(void* const* d_in, const int* in_sizes, int n_in,
                              void* d_out, int out_size, void* d_ws, size_t ws_size,
                              hipStream_t stream) {
    const float* x = (const float*)d_in[0];
    const int* shifts = (const int*)d_in[1];
    float* out = (float*)d_out;

    const int B = in_sizes[1];
    const int T = in_sizes[0] / B;

    if ((T & 3) == 0) {
        const int TQ = T >> 2;
        dim3 block(256);
        dim3 grid((TQ + 256 * QPT - 1) / (256 * QPT), B);
        roll_rows_ux4<<<grid, block, 0, stream>>>(x, shifts, out, T);
    } else {
        dim3 block(256);
        dim3 grid((T + 255) / 256, B);
        roll_rows_scalar<<<grid, block, 0, stream>>>(x, shifts, out, T);
    }
}